// Round 10
// baseline (128.467 us; speedup 1.0000x reference)
//
#include <hip/hip_runtime.h>

#define BATCH 10000
#define NCH 64
#define DIM_IN 16
#define DIM_OUT 99

typedef float f32x4 __attribute__((ext_vector_type(4)));

// ---------------- compile-time CG construction (C++17 constexpr) ----------------
namespace cgc {

struct cx { double re; double im; };

constexpr cx cmul(cx a, cx b) {
    return cx{a.re * b.re - a.im * b.im, a.re * b.im + a.im * b.re};
}

constexpr double cfact(int n) {
    double r = 1.0;
    for (int i = 2; i <= n; ++i) r *= (double)i;
    return r;
}

constexpr double csqrt(double x) {
    if (x <= 0.0) return 0.0;
    double y = x > 1.0 ? x : 1.0;
    for (int i = 0; i < 100; ++i) y = 0.5 * (y + x / y);
    return y;
}

constexpr int imax(int a, int b) { return a > b ? a : b; }
constexpr int imin(int a, int b) { return a < b ? a : b; }
constexpr int iabs(int a) { return a < 0 ? -a : a; }

// Racah formula (exact ratios of factorials <= 10! in double)
constexpr double su2_cg(int j1, int m1, int j2, int m2, int j3, int m3) {
    if (m3 != m1 + m2) return 0.0;
    if (j3 < iabs(j1 - j2) || j3 > j1 + j2) return 0.0;
    int vmin = imax(imax(-j1 + j2 + m3, -j1 + m1), 0);
    int vmax = imin(imin(j2 + j3 + m1, j3 - j1 + j2), j3 + m3);
    double C = (2.0 * j3 + 1.0) *
        (cfact(j3 + j1 - j2) * cfact(j3 - j1 + j2) * cfact(j1 + j2 - j3) *
         cfact(j3 + m3) * cfact(j3 - m3)) /
        (cfact(j1 + j2 + j3 + 1) * cfact(j1 - m1) * cfact(j1 + m1) *
         cfact(j2 - m2) * cfact(j2 + m2));
    double S = 0.0;
    for (int v = vmin; v <= vmax; ++v) {
        double t = (cfact(j2 + j3 + m1 - v) * cfact(j1 - m1 + v)) /
                   (cfact(v) * cfact(j3 - j1 + j2 - v) * cfact(j3 + m3 - v) *
                    cfact(v + j1 - j2 - m3));
        S += ((v + j2 + m2) & 1) ? -t : t;
    }
    return csqrt(C) * S;
}

// real SH -> complex SH basis change (matches e3nn, incl. (-i)^l phase)
constexpr void fill_q(int l, cx* q) {
    const int n = 2 * l + 1;
    const double is2 = 0.70710678118654752440;
    for (int e = 0; e < n * n; ++e) q[e] = cx{0.0, 0.0};
    for (int m = -l; m < 0; ++m) {
        q[(l + m) * n + (l - m)] = cx{is2, 0.0};
        q[(l + m) * n + (l + m)] = cx{0.0, -is2};
    }
    q[l * n + l] = cx{1.0, 0.0};
    for (int m = 1; m <= l; ++m) {
        double s = (m & 1) ? -1.0 : 1.0;
        q[(l + m) * n + (l + m)] = cx{s * is2, 0.0};
        q[(l + m) * n + (l - m)] = cx{0.0, s * is2};
    }
    cx ph = (l & 3) == 0 ? cx{1.0, 0.0}
          : (l & 3) == 1 ? cx{0.0, -1.0}
          : (l & 3) == 2 ? cx{-1.0, 0.0}
                         : cx{0.0, 1.0};
    for (int e = 0; e < n * n; ++e) q[e] = cmul(ph, q[e]);
}

template<int l1, int l2, int l3>
struct InstCG { float v[(2 * l1 + 1) * (2 * l2 + 1) * (2 * l3 + 1)]; };

// real-basis wigner_3j * sqrt(2*l3+1), unit Frobenius norm before scaling
template<int l1, int l2, int l3>
constexpr InstCG<l1, l2, l3> make_inst() {
    constexpr int n1 = 2 * l1 + 1, n2 = 2 * l2 + 1, n3 = 2 * l3 + 1;
    double C[n1 * n2 * n3] = {};
    for (int i = 0; i < n1; ++i)
        for (int k = 0; k < n2; ++k)
            for (int nn = 0; nn < n3; ++nn)
                C[(i * n2 + k) * n3 + nn] = su2_cg(l1, i - l1, l2, k - l2, l3, nn - l3);
    cx Q1[n1 * n1] = {}; cx Q2[n2 * n2] = {}; cx Q3[n3 * n3] = {};
    fill_q(l1, Q1); fill_q(l2, Q2); fill_q(l3, Q3);
    double R[n1 * n2 * n3] = {};
    double ss = 0.0;
    for (int j = 0; j < n1; ++j)
        for (int lc = 0; lc < n2; ++lc)
            for (int m = 0; m < n3; ++m) {
                double ar = 0.0;
                for (int i = 0; i < n1; ++i) {
                    cx q1 = Q1[i * n1 + j];
                    if (q1.re == 0.0 && q1.im == 0.0) continue;
                    for (int k = 0; k < n2; ++k) {
                        cx q12 = cmul(q1, Q2[k * n2 + lc]);
                        if (q12.re == 0.0 && q12.im == 0.0) continue;
                        for (int nn = 0; nn < n3; ++nn) {
                            double cc = C[(i * n2 + k) * n3 + nn];
                            if (cc == 0.0) continue;
                            cx q3 = Q3[nn * n3 + m];
                            ar += (q12.re * q3.re + q12.im * q3.im) * cc;
                        }
                    }
                }
                R[(j * n2 + lc) * n3 + m] = ar;
                ss += ar * ar;
            }
    double scale = csqrt((double)n3) / csqrt(ss);
    InstCG<l1, l2, l3> T{};
    for (int e = 0; e < n1 * n2 * n3; ++e) T.v[e] = (float)(R[e] * scale);
    return T;
}

}  // namespace cgc

// CEILING PROBE: exact traffic profile of tp_main (80MB unique NT reads,
// 253MB unique cached writes) with IDEAL fill-like dense sequential pattern.
// Each input vec4 read exactly once per pass; each output vec4 written once.
__global__ __launch_bounds__(256) void synth_stream(const float* __restrict__ x,
                                                    const float* __restrict__ y,
                                                    float* __restrict__ out) {
    const size_t N4 = (size_t)BATCH * DIM_OUT * NCH / 4;   // 15,840,000 vec4 writes
    const size_t R4 = (size_t)BATCH * DIM_IN * NCH / 4;    //  2,560,000 vec4 per input
    const f32x4* x4 = reinterpret_cast<const f32x4*>(x);
    const f32x4* y4 = reinterpret_cast<const f32x4*>(y);
    f32x4* o4 = reinterpret_cast<f32x4*>(out);
    const size_t stride = (size_t)gridDim.x * blockDim.x;
    for (size_t i = (size_t)blockIdx.x * blockDim.x + threadIdx.x; i < N4; i += stride) {
        f32x4 v;
        if (i < R4) {
            const f32x4 a = __builtin_nontemporal_load(&x4[i]);
            const f32x4 b = __builtin_nontemporal_load(&y4[i]);
            v = a + b;
        } else {
            v = (f32x4)(float)(i & 1023);   // register-only, no read
        }
        o4[i] = v;   // cached store, dense sequential across the grid
    }
}

// One instruction. xv = all 16 x rows in regs; ybl = this l2-block's y rows
// (local index m2). Each output slot written exactly once, plain cached store.
template<int l1, int l2, int l3, int o1, int o3>
__device__ __forceinline__ void do_inst(const f32x4* xv, const f32x4* ybl, f32x4* o4) {
    constexpr int n1 = 2 * l1 + 1, n2 = 2 * l2 + 1, n3 = 2 * l3 + 1;
    constexpr cgc::InstCG<l1, l2, l3> T = cgc::make_inst<l1, l2, l3>();
    f32x4 acc[n3];
#pragma unroll
    for (int m3 = 0; m3 < n3; ++m3) acc[m3] = (f32x4)0.0f;
#pragma unroll
    for (int m1 = 0; m1 < n1; ++m1) {
#pragma unroll
        for (int m2 = 0; m2 < n2; ++m2) {
            const f32x4 p = xv[o1 + m1] * ybl[m2];
#pragma unroll
            for (int m3 = 0; m3 < n3; ++m3) {
                const float c = T.v[(m1 * n2 + m2) * n3 + m3];
                if (c != 0.0f) acc[m3] += c * p;
            }
        }
    }
#pragma unroll
    for (int m3 = 0; m3 < n3; ++m3)
        o4[(o3 + m3) * 16] = acc[m3];   // plain cached store
}

// EXACT R8 kernel (67.9us known): NT loads + cached stores.
__global__ __launch_bounds__(64, 3) void tp_main(const float* __restrict__ x,
                                                 const float* __restrict__ y,
                                                 float* __restrict__ out) {
    const int g = blockIdx.x * blockDim.x + threadIdx.x;  // exact grid
    const int b = g >> 4;   // batch row
    const int cl = g & 15;  // channel quad

    const f32x4* x4 = reinterpret_cast<const f32x4*>(x + (size_t)b * (DIM_IN * NCH)) + cl;
    const f32x4* y4 = reinterpret_cast<const f32x4*>(y + (size_t)b * (DIM_IN * NCH)) + cl;
    f32x4* o4 = reinterpret_cast<f32x4*>(out + (size_t)b * (DIM_OUT * NCH)) + cl;

    f32x4 xv[DIM_IN];
#pragma unroll
    for (int i = 0; i < DIM_IN; ++i) xv[i] = __builtin_nontemporal_load(&x4[i * 16]);

    // l2 = 0 : y row 0
    {
        f32x4 ybl[1];
        ybl[0] = __builtin_nontemporal_load(&y4[0 * 16]);
        do_inst<0,0,0, 0,0 >(xv, ybl, o4);
        do_inst<1,0,1, 1,16>(xv, ybl, o4);
        do_inst<2,0,2, 4,40>(xv, ybl, o4);
        do_inst<3,0,3, 9,71>(xv, ybl, o4);
    }
    // l2 = 1 : y rows 1..3
    {
        f32x4 ybl[3];
#pragma unroll
        for (int k = 0; k < 3; ++k) ybl[k] = __builtin_nontemporal_load(&y4[(1 + k) * 16]);
        do_inst<0,1,1, 0,1 >(xv, ybl, o4);
        do_inst<1,1,0, 1,19>(xv, ybl, o4);
        do_inst<1,1,2, 1,20>(xv, ybl, o4);
        do_inst<2,1,1, 4,45>(xv, ybl, o4);
        do_inst<2,1,3, 4,48>(xv, ybl, o4);
        do_inst<3,1,2, 9,78>(xv, ybl, o4);
    }
    // l2 = 2 : y rows 4..8
    {
        f32x4 ybl[5];
#pragma unroll
        for (int k = 0; k < 5; ++k) ybl[k] = __builtin_nontemporal_load(&y4[(4 + k) * 16]);
        do_inst<0,2,2, 0,4 >(xv, ybl, o4);
        do_inst<1,2,1, 1,25>(xv, ybl, o4);
        do_inst<1,2,3, 1,28>(xv, ybl, o4);
        do_inst<2,2,0, 4,55>(xv, ybl, o4);
        do_inst<2,2,2, 4,56>(xv, ybl, o4);
        do_inst<3,2,1, 9,83>(xv, ybl, o4);
        do_inst<3,2,3, 9,86>(xv, ybl, o4);
    }
    // l2 = 3 : y rows 9..15
    {
        f32x4 ybl[7];
#pragma unroll
        for (int k = 0; k < 7; ++k) ybl[k] = __builtin_nontemporal_load(&y4[(9 + k) * 16]);
        do_inst<0,3,3, 0,9 >(xv, ybl, o4);
        do_inst<1,3,2, 1,35>(xv, ybl, o4);
        do_inst<2,3,1, 4,61>(xv, ybl, o4);
        do_inst<2,3,3, 4,64>(xv, ybl, o4);
        do_inst<3,3,0, 9,93>(xv, ybl, o4);
        do_inst<3,3,2, 9,94>(xv, ybl, o4);
    }
}

extern "C" void kernel_launch(void* const* d_in, const int* in_sizes, int n_in,
                              void* d_out, int out_size, void* d_ws, size_t ws_size,
                              hipStream_t stream) {
    const float* x = (const float*)d_in[0];
    const float* y = (const float*)d_in[1];
    float* out = (float*)d_out;
    // 1) ceiling probe: ideal-pattern streamer with tp_main's exact traffic
    //    profile (garbage into out). 2) exact R8 tp_main overwrites correctly.
    //    synth_t = dur_total - 67.9us.
    hipLaunchKernelGGL(synth_stream, dim3(2048), dim3(256), 0, stream, x, y, out);
    hipLaunchKernelGGL(tp_main, dim3(BATCH * 16 / 64), dim3(64), 0, stream,
                       x, y, out);
}

// Round 11
// 67.108 us; speedup vs baseline: 1.9143x; 1.9143x over previous
//
#include <hip/hip_runtime.h>

#define BATCH 10000
#define NCH 64
#define DIM_IN 16
#define DIM_OUT 99

typedef float f32x4 __attribute__((ext_vector_type(4)));

// ---------------- compile-time CG construction (C++17 constexpr) ----------------
namespace cgc {

struct cx { double re; double im; };

constexpr cx cmul(cx a, cx b) {
    return cx{a.re * b.re - a.im * b.im, a.re * b.im + a.im * b.re};
}

constexpr double cfact(int n) {
    double r = 1.0;
    for (int i = 2; i <= n; ++i) r *= (double)i;
    return r;
}

constexpr double csqrt(double x) {
    if (x <= 0.0) return 0.0;
    double y = x > 1.0 ? x : 1.0;
    for (int i = 0; i < 100; ++i) y = 0.5 * (y + x / y);
    return y;
}

constexpr int imax(int a, int b) { return a > b ? a : b; }
constexpr int imin(int a, int b) { return a < b ? a : b; }
constexpr int iabs(int a) { return a < 0 ? -a : a; }

// Racah formula (exact ratios of factorials <= 10! in double)
constexpr double su2_cg(int j1, int m1, int j2, int m2, int j3, int m3) {
    if (m3 != m1 + m2) return 0.0;
    if (j3 < iabs(j1 - j2) || j3 > j1 + j2) return 0.0;
    int vmin = imax(imax(-j1 + j2 + m3, -j1 + m1), 0);
    int vmax = imin(imin(j2 + j3 + m1, j3 - j1 + j2), j3 + m3);
    double C = (2.0 * j3 + 1.0) *
        (cfact(j3 + j1 - j2) * cfact(j3 - j1 + j2) * cfact(j1 + j2 - j3) *
         cfact(j3 + m3) * cfact(j3 - m3)) /
        (cfact(j1 + j2 + j3 + 1) * cfact(j1 - m1) * cfact(j1 + m1) *
         cfact(j2 - m2) * cfact(j2 + m2));
    double S = 0.0;
    for (int v = vmin; v <= vmax; ++v) {
        double t = (cfact(j2 + j3 + m1 - v) * cfact(j1 - m1 + v)) /
                   (cfact(v) * cfact(j3 - j1 + j2 - v) * cfact(j3 + m3 - v) *
                    cfact(v + j1 - j2 - m3));
        S += ((v + j2 + m2) & 1) ? -t : t;
    }
    return csqrt(C) * S;
}

// real SH -> complex SH basis change (matches e3nn, incl. (-i)^l phase)
constexpr void fill_q(int l, cx* q) {
    const int n = 2 * l + 1;
    const double is2 = 0.70710678118654752440;
    for (int e = 0; e < n * n; ++e) q[e] = cx{0.0, 0.0};
    for (int m = -l; m < 0; ++m) {
        q[(l + m) * n + (l - m)] = cx{is2, 0.0};
        q[(l + m) * n + (l + m)] = cx{0.0, -is2};
    }
    q[l * n + l] = cx{1.0, 0.0};
    for (int m = 1; m <= l; ++m) {
        double s = (m & 1) ? -1.0 : 1.0;
        q[(l + m) * n + (l + m)] = cx{s * is2, 0.0};
        q[(l + m) * n + (l - m)] = cx{0.0, s * is2};
    }
    cx ph = (l & 3) == 0 ? cx{1.0, 0.0}
          : (l & 3) == 1 ? cx{0.0, -1.0}
          : (l & 3) == 2 ? cx{-1.0, 0.0}
                         : cx{0.0, 1.0};
    for (int e = 0; e < n * n; ++e) q[e] = cmul(ph, q[e]);
}

template<int l1, int l2, int l3>
struct InstCG { float v[(2 * l1 + 1) * (2 * l2 + 1) * (2 * l3 + 1)]; };

// real-basis wigner_3j * sqrt(2*l3+1), unit Frobenius norm before scaling
template<int l1, int l2, int l3>
constexpr InstCG<l1, l2, l3> make_inst() {
    constexpr int n1 = 2 * l1 + 1, n2 = 2 * l2 + 1, n3 = 2 * l3 + 1;
    double C[n1 * n2 * n3] = {};
    for (int i = 0; i < n1; ++i)
        for (int k = 0; k < n2; ++k)
            for (int nn = 0; nn < n3; ++nn)
                C[(i * n2 + k) * n3 + nn] = su2_cg(l1, i - l1, l2, k - l2, l3, nn - l3);
    cx Q1[n1 * n1] = {}; cx Q2[n2 * n2] = {}; cx Q3[n3 * n3] = {};
    fill_q(l1, Q1); fill_q(l2, Q2); fill_q(l3, Q3);
    double R[n1 * n2 * n3] = {};
    double ss = 0.0;
    for (int j = 0; j < n1; ++j)
        for (int lc = 0; lc < n2; ++lc)
            for (int m = 0; m < n3; ++m) {
                double ar = 0.0;
                for (int i = 0; i < n1; ++i) {
                    cx q1 = Q1[i * n1 + j];
                    if (q1.re == 0.0 && q1.im == 0.0) continue;
                    for (int k = 0; k < n2; ++k) {
                        cx q12 = cmul(q1, Q2[k * n2 + lc]);
                        if (q12.re == 0.0 && q12.im == 0.0) continue;
                        for (int nn = 0; nn < n3; ++nn) {
                            double cc = C[(i * n2 + k) * n3 + nn];
                            if (cc == 0.0) continue;
                            cx q3 = Q3[nn * n3 + m];
                            ar += (q12.re * q3.re + q12.im * q3.im) * cc;
                        }
                    }
                }
                R[(j * n2 + lc) * n3 + m] = ar;
                ss += ar * ar;
            }
    double scale = csqrt((double)n3) / csqrt(ss);
    InstCG<l1, l2, l3> T{};
    for (int e = 0; e < n1 * n2 * n3; ++e) T.v[e] = (float)(R[e] * scale);
    return T;
}

}  // namespace cgc

// One instruction. xl = local x-row array (o1l = local offset of this l1
// group); ybl = this l2-block's y rows. Each output slot written exactly
// once: NT loads + plain cached stores (R8/R9 proven winning combo).
template<int l1, int l2, int l3, int o1l, int o3>
__device__ __forceinline__ void do_inst(const f32x4* xl, const f32x4* ybl, f32x4* o4) {
    constexpr int n1 = 2 * l1 + 1, n2 = 2 * l2 + 1, n3 = 2 * l3 + 1;
    constexpr cgc::InstCG<l1, l2, l3> T = cgc::make_inst<l1, l2, l3>();
    f32x4 acc[n3];
#pragma unroll
    for (int m3 = 0; m3 < n3; ++m3) acc[m3] = (f32x4)0.0f;
#pragma unroll
    for (int m1 = 0; m1 < n1; ++m1) {
#pragma unroll
        for (int m2 = 0; m2 < n2; ++m2) {
            const f32x4 p = xl[o1l + m1] * ybl[m2];
#pragma unroll
            for (int m3 = 0; m3 < n3; ++m3) {
                const float c = T.v[(m1 * n2 + m2) * n3 + m3];
                if (c != 0.0f) acc[m3] += c * p;
            }
        }
    }
#pragma unroll
    for (int m3 = 0; m3 < n3; ++m3)
        o4[(o3 + m3) * 16] = acc[m3];   // plain cached store
}

// PARALLELISM-SPLIT vs R8 (67.9us): each batch-row's 23 instructions split
// across TWO waves by l1 parity -> 5000 waves (~4.9/SIMD vs 2.4) for store
// latency hiding. Half A: l1 in {0,2} (x rows {0,4..8}, slots 0-15 & 40-70);
// half B: l1 in {1,3} (x rows {1-3,9-15}, slots 16-39 & 71-98). Halves
// interleaved by blockIdx parity so the doubled y reads are L2/L3 hits.
// Branch is wave-uniform. Flags: NT loads + cached stores (proven combo).
__global__ __launch_bounds__(64, 3) void tp_main(const float* __restrict__ x,
                                                 const float* __restrict__ y,
                                                 float* __restrict__ out) {
    const int bid = blockIdx.x;
    const int half = bid & 1;                 // wave-uniform
    const int g = (bid >> 1) * 64 + threadIdx.x;
    const int b = g >> 4;   // batch row
    const int cl = g & 15;  // channel quad

    const f32x4* x4 = reinterpret_cast<const f32x4*>(x + (size_t)b * (DIM_IN * NCH)) + cl;
    const f32x4* y4 = reinterpret_cast<const f32x4*>(y + (size_t)b * (DIM_IN * NCH)) + cl;
    f32x4* o4 = reinterpret_cast<f32x4*>(out + (size_t)b * (DIM_OUT * NCH)) + cl;

    if (half == 0) {
        // ---- half A: l1 in {0,2}; x rows {0, 4..8} -> xl[0], xl[1..5] ----
        f32x4 xl[6];
        xl[0] = __builtin_nontemporal_load(&x4[0 * 16]);
#pragma unroll
        for (int k = 0; k < 5; ++k) xl[1 + k] = __builtin_nontemporal_load(&x4[(4 + k) * 16]);

        {   // l2 = 0 : y row 0
            f32x4 ybl[1];
            ybl[0] = __builtin_nontemporal_load(&y4[0 * 16]);
            do_inst<0,0,0, 0,0 >(xl, ybl, o4);
            do_inst<2,0,2, 1,40>(xl, ybl, o4);
        }
        {   // l2 = 1 : y rows 1..3
            f32x4 ybl[3];
#pragma unroll
            for (int k = 0; k < 3; ++k) ybl[k] = __builtin_nontemporal_load(&y4[(1 + k) * 16]);
            do_inst<0,1,1, 0,1 >(xl, ybl, o4);
            do_inst<2,1,1, 1,45>(xl, ybl, o4);
            do_inst<2,1,3, 1,48>(xl, ybl, o4);
        }
        {   // l2 = 2 : y rows 4..8
            f32x4 ybl[5];
#pragma unroll
            for (int k = 0; k < 5; ++k) ybl[k] = __builtin_nontemporal_load(&y4[(4 + k) * 16]);
            do_inst<0,2,2, 0,4 >(xl, ybl, o4);
            do_inst<2,2,0, 1,55>(xl, ybl, o4);
            do_inst<2,2,2, 1,56>(xl, ybl, o4);
        }
        {   // l2 = 3 : y rows 9..15
            f32x4 ybl[7];
#pragma unroll
            for (int k = 0; k < 7; ++k) ybl[k] = __builtin_nontemporal_load(&y4[(9 + k) * 16]);
            do_inst<0,3,3, 0,9 >(xl, ybl, o4);
            do_inst<2,3,1, 1,61>(xl, ybl, o4);
            do_inst<2,3,3, 1,64>(xl, ybl, o4);
        }
    } else {
        // ---- half B: l1 in {1,3}; x rows {1..3, 9..15} -> xl[0..2], xl[3..9] ----
        f32x4 xl[10];
#pragma unroll
        for (int k = 0; k < 3; ++k) xl[k] = __builtin_nontemporal_load(&x4[(1 + k) * 16]);
#pragma unroll
        for (int k = 0; k < 7; ++k) xl[3 + k] = __builtin_nontemporal_load(&x4[(9 + k) * 16]);

        {   // l2 = 0 : y row 0
            f32x4 ybl[1];
            ybl[0] = __builtin_nontemporal_load(&y4[0 * 16]);
            do_inst<1,0,1, 0,16>(xl, ybl, o4);
            do_inst<3,0,3, 3,71>(xl, ybl, o4);
        }
        {   // l2 = 1 : y rows 1..3
            f32x4 ybl[3];
#pragma unroll
            for (int k = 0; k < 3; ++k) ybl[k] = __builtin_nontemporal_load(&y4[(1 + k) * 16]);
            do_inst<1,1,0, 0,19>(xl, ybl, o4);
            do_inst<1,1,2, 0,20>(xl, ybl, o4);
            do_inst<3,1,2, 3,78>(xl, ybl, o4);
        }
        {   // l2 = 2 : y rows 4..8
            f32x4 ybl[5];
#pragma unroll
            for (int k = 0; k < 5; ++k) ybl[k] = __builtin_nontemporal_load(&y4[(4 + k) * 16]);
            do_inst<1,2,1, 0,25>(xl, ybl, o4);
            do_inst<1,2,3, 0,28>(xl, ybl, o4);
            do_inst<3,2,1, 3,83>(xl, ybl, o4);
            do_inst<3,2,3, 3,86>(xl, ybl, o4);
        }
        {   // l2 = 3 : y rows 9..15
            f32x4 ybl[7];
#pragma unroll
            for (int k = 0; k < 7; ++k) ybl[k] = __builtin_nontemporal_load(&y4[(9 + k) * 16]);
            do_inst<1,3,2, 0,35>(xl, ybl, o4);
            do_inst<3,3,0, 3,93>(xl, ybl, o4);
            do_inst<3,3,2, 3,94>(xl, ybl, o4);
        }
    }
}

extern "C" void kernel_launch(void* const* d_in, const int* in_sizes, int n_in,
                              void* d_out, int out_size, void* d_ws, size_t ws_size,
                              hipStream_t stream) {
    const float* x = (const float*)d_in[0];
    const float* y = (const float*)d_in[1];
    float* out = (float*)d_out;
    hipLaunchKernelGGL(tp_main, dim3(BATCH * 16 / 64 * 2), dim3(64), 0, stream,
                       x, y, out);
}